// Round 7
// baseline (155.947 us; speedup 1.0000x reference)
//
#include <hip/hip_runtime.h>
#include <hip/hip_bf16.h>

typedef __attribute__((ext_vector_type(8))) short bf16x8;   // 8 bf16 = 4 VGPR (MFMA A/B frag)
typedef __attribute__((ext_vector_type(4))) float f32x4;    // MFMA C/D frag

#define DEVI __device__ __forceinline__

constexpr int SEQ_   = 2048;
constexpr int HEADS  = 16;
constexpr int DHEAD  = 64;
constexpr int DMODEL = 1024;

DEVI unsigned short f2bf(float x) {
  __hip_bfloat16 h = __float2bfloat16(x);   // RNE
  return __builtin_bit_cast(unsigned short, h);
}

DEVI f32x4 MFMA(bf16x8 a, bf16x8 b, f32x4 c) {
  return __builtin_amdgcn_mfma_f32_16x16x32_bf16(a, b, c, 0, 0, 0);
}

// ---------------------------------------------------------------- convert ---
__global__ void conv3_kernel(const float* s0, const float* s1, const float* s2,
                             unsigned short* d0, unsigned short* d1, unsigned short* d2,
                             int n) {
  const float* s = (blockIdx.y == 0) ? s0 : (blockIdx.y == 1) ? s1 : s2;
  unsigned short* d = (blockIdx.y == 0) ? d0 : (blockIdx.y == 1) ? d1 : d2;
  int i = (blockIdx.x * 256 + threadIdx.x) * 8;
  if (i >= n) return;
  const float4* p = (const float4*)(s + i);
  float4 v0 = p[0], v1 = p[1];
  union { unsigned short u[8]; bf16x8 v; } t;
  t.u[0] = f2bf(v0.x); t.u[1] = f2bf(v0.y); t.u[2] = f2bf(v0.z); t.u[3] = f2bf(v0.w);
  t.u[4] = f2bf(v1.x); t.u[5] = f2bf(v1.y); t.u[6] = f2bf(v1.z); t.u[7] = f2bf(v1.w);
  *(bf16x8*)(d + i) = t.v;
}

// ------------------------------------------------------------- projection ---
// z==0 (Q): out (b,h,s,d), PRE-SCALED by 0.125 (folds the 1/sqrt(dh)).
// z==1 (K): 4KB tiles in MFMA fragment order (see R6 derivation).
// z==2 (V): 4KB tiles in MFMA fragment order.
__global__ __launch_bounds__(256) void proj3_kernel(
    const unsigned short* __restrict__ X0, const unsigned short* __restrict__ X1,
    const unsigned short* __restrict__ X2,
    const unsigned short* __restrict__ W0, const unsigned short* __restrict__ W1,
    const unsigned short* __restrict__ W2,
    const float* __restrict__ bi0, const float* __restrict__ bi1,
    const float* __restrict__ bi2,
    unsigned short* __restrict__ o0, unsigned short* __restrict__ o1,
    unsigned short* __restrict__ o2) {
  const int z = blockIdx.z;
  const unsigned short* X = (z == 0) ? X0 : (z == 1) ? X1 : X2;
  const unsigned short* W = (z == 0) ? W0 : (z == 1) ? W1 : W2;
  const float* bias        = (z == 0) ? bi0 : (z == 1) ? bi1 : bi2;
  unsigned short* out      = (z == 0) ? o0 : (z == 1) ? o1 : o2;

  __shared__ unsigned short Abuf[2][128 * 32];
  __shared__ unsigned short Bbuf[2][128 * 32];
  const int tid  = threadIdx.x;
  const int lane = tid & 63, wv = tid >> 6;
  const int q = lane >> 4, r = lane & 15;
  const int wrow = wv >> 1, wcol = wv & 1;
  const int rowA0 = blockIdx.x * 128, colB0 = blockIdx.y * 128;

  const char* Ag = (const char*)(X + (size_t)rowA0 * DMODEL);
  const char* Bg = (const char*)(W + (size_t)colB0 * DMODEL);

  f32x4 acc[4][4] = {};

  auto stage = [&](int ks, int buf) {
    const int koff = ks * 64;
#pragma unroll
    for (int i = 0; i < 2; ++i) {
      const int b   = (i * 256 + tid) * 16;
      const int row = b >> 6, col = b & 63;
      __builtin_amdgcn_global_load_lds(
          (const __attribute__((address_space(1))) void*)(Ag + (size_t)row * (DMODEL * 2) + koff + col),
          (__attribute__((address_space(3))) void*)((char*)&Abuf[buf][0] + i * 4096 + wv * 1024),
          16, 0, 0);
      __builtin_amdgcn_global_load_lds(
          (const __attribute__((address_space(1))) void*)(Bg + (size_t)row * (DMODEL * 2) + koff + col),
          (__attribute__((address_space(3))) void*)((char*)&Bbuf[buf][0] + i * 4096 + wv * 1024),
          16, 0, 0);
    }
  };

  stage(0, 0);
  for (int ks = 0; ks < 32; ++ks) {
    __syncthreads();
    if (ks + 1 < 32) stage(ks + 1, (ks + 1) & 1);
    const unsigned short* A  = &Abuf[ks & 1][0];
    const unsigned short* Bt = &Bbuf[ks & 1][0];
    bf16x8 af[4], bfr[4];
#pragma unroll
    for (int t = 0; t < 4; ++t) {
      af[t]  = *(const bf16x8*)(A  + (wrow * 64 + t * 16 + r) * 32 + q * 8);
      bfr[t] = *(const bf16x8*)(Bt + (wcol * 64 + t * 16 + r) * 32 + q * 8);
    }
#pragma unroll
    for (int m = 0; m < 4; ++m)
#pragma unroll
      for (int n = 0; n < 4; ++n)
        acc[m][n] = MFMA(af[m], bfr[n], acc[m][n]);
  }

#pragma unroll
  for (int m = 0; m < 4; ++m) {
#pragma unroll
    for (int n = 0; n < 4; ++n) {
      const int e  = colB0 + wcol * 64 + n * 16 + r;
      const float bv = bias[e];
      const int h = e >> 6, dd = e & 63;
      const int nrow0 = rowA0 + wrow * 64 + m * 16 + q * 4;
      const int bb = nrow0 >> 11, ss0 = nrow0 & 2047;
      const size_t bh = (size_t)(bb * HEADS + h);
      if (z == 0) {
#pragma unroll
        for (int j = 0; j < 4; ++j)
          out[(bh * SEQ_ + (ss0 + j)) * DHEAD + dd] = f2bf((acc[m][n][j] + bv) * 0.125f);
      } else if (z == 1) {
#pragma unroll
        for (int j = 0; j < 4; ++j) {
          const int s = ss0 + j;
          const size_t off = (bh * 64 + (size_t)(s >> 5)) * 2048
                           + (size_t)(((dd >> 5) * 2 + ((s >> 4) & 1)) * 512)
                           + (size_t)(((((dd & 31) >> 3) << 4) + (s & 15)) * 8)
                           + (dd & 7);
          out[off] = f2bf(acc[m][n][j] + bv);
        }
      } else {
        union { unsigned short u[4]; uint2 v; } pk;
#pragma unroll
        for (int j = 0; j < 4; ++j) pk.u[j] = f2bf(acc[m][n][j] + bv);
        const size_t off = (bh * 64 + (size_t)(ss0 >> 5)) * 2048
                         + (size_t)((dd >> 4) * 512)
                         + (size_t)(((((ss0 & 31) >> 3) << 4) + (dd & 15)) * 8)
                         + (ss0 & 7);
        *(uint2*)&out[off] = pk.v;
      }
    }
  }
}

// -------------------------------------------------------------- attention ---
// STAGING-BW-BOUND fix: 128-row q-blocks (4 waves x 32 rows) amortize each
// 16KB K/V stage over 4x the work (R5/R6 showed ~19B/cyc/CU DMA ceiling).
// 512 blocks x 256 thr. Pair (L=15-p, S=p); each tile's K-iters split
// even/odd between ab=0/1 blocks -> every block exactly 34 iters AND even
// per-wave active fractions. Fixed-max softmax partials merged by reduce.
// Per wave: 32 rows, qer lattice m=1..4 recomputed per iter (stride-2 K),
// skew gather = 3 shfl + one lane-static select (r > q*4+j) per (rt,j).
__global__ __launch_bounds__(256, 2) void attn_kernel(
    const unsigned short* __restrict__ qb, const unsigned short* __restrict__ kt,
    const unsigned short* __restrict__ vt, const unsigned short* __restrict__ Er,
    float* __restrict__ pO, float* __restrict__ pL) {
  __shared__ unsigned short k_lds[2][2048];     // frag-order 4KB tile per buf
  __shared__ unsigned short v_lds[2][2048];
  __shared__ unsigned short p_lds[4][32][40];   // per-wave P bounce

  const int tid  = threadIdx.x;
  const int lane = tid & 63, wv = tid >> 6;
  const int q = lane >> 4, r = lane & 15;

  const int lid = blockIdx.x;
  const int xcd = lid & 7, idx = lid >> 3;      // 64 blocks per XCD
  const int bh  = (xcd << 2) | (idx & 3);       // 4 bh pinned per XCD L2
  const int rest = idx >> 2;                    // 0..15
  const int pairp = rest >> 1, ab = rest & 1;

  const unsigned short* qbh = qb + (size_t)bh * SEQ_ * DHEAD;
  const char* ktb = (const char*)(kt + (size_t)bh * 64 * 2048);
  const char* vtb = (const char*)(vt + (size_t)bh * 64 * 2048);

  const f32x4 zero4 = {0.f, 0.f, 0.f, 0.f};

  auto stage = [&](int kt2, int buf) {
    __builtin_amdgcn_global_load_lds(
        (const __attribute__((address_space(1))) void*)(ktb + (size_t)kt2 * 4096 + tid * 16),
        (__attribute__((address_space(3))) void*)((char*)&k_lds[buf][0] + wv * 1024),
        16, 0, 0);
    __builtin_amdgcn_global_load_lds(
        (const __attribute__((address_space(1))) void*)(vtb + (size_t)kt2 * 4096 + tid * 16),
        (__attribute__((address_space(3))) void*)((char*)&v_lds[buf][0] + wv * 1024),
        16, 0, 0);
  };

  auto run_strip = [&](int T, float* po, float* pl) {
    const int s0 = T * 128 + wv * 32;
    const int nK = 2 * T + 2;                   // this ab's iteration count
    __syncthreads();                            // prev strip done with bufs
    stage(ab, 0);

    bf16x8 qf[2][2];
#pragma unroll
    for (int rt = 0; rt < 2; ++rt) {
      qf[rt][0] = *(const bf16x8*)(qbh + (size_t)(s0 + rt * 16 + r) * DHEAD + q * 8);
      qf[rt][1] = *(const bf16x8*)(qbh + (size_t)(s0 + rt * 16 + r) * DHEAD + 32 + q * 8);
    }
    f32x4 oacc[2][4] = {};
    float lpart[2][4] = {};

#pragma unroll 1
    for (int k = 0; k < nK; ++k) {
      const int buf = k & 1;
      const int t0 = (2 * k + ab) * 32;
      const bool active = (t0 <= s0 + 31);
      __syncthreads();                          // buf staged (issued last iter)
      if (k + 1 < nK) stage(2 * (k + 1) + ab, buf ^ 1);  // fire-and-forget
      if (!active) continue;                    // all threads still hit barriers

      // Er loads for lattice tiles m=1..4 (shared across rt); clamp feeds
      // only masked positions (l>2047 <=> t>s).
      const int L0 = 2000 + t0 - s0;
      bf16x8 ef[4][2];
#pragma unroll
      for (int m = 0; m < 4; ++m) {
        int l = L0 + 16 * (m + 1) + r; l = l < 2047 ? l : 2047;
        ef[m][0] = *(const bf16x8*)(Er + (size_t)l * DHEAD + q * 8);
        ef[m][1] = *(const bf16x8*)(Er + (size_t)l * DHEAD + 32 + q * 8);
      }

      const unsigned short* KL = &k_lds[buf][0];
      const unsigned short* VL = &v_lds[buf][0];
      bf16x8 kf00 = *(const bf16x8*)(KL + lane * 8);          // (ct0,kc0)
      bf16x8 kf10 = *(const bf16x8*)(KL + 512 + lane * 8);    // (ct1,kc0)
      bf16x8 kf01 = *(const bf16x8*)(KL + 1024 + lane * 8);   // (ct0,kc1)
      bf16x8 kf11 = *(const bf16x8*)(KL + 1536 + lane * 8);   // (ct1,kc1)

      f32x4 s4[2][2], qer[2][4];
      __builtin_amdgcn_s_setprio(1);
#pragma unroll
      for (int rt = 0; rt < 2; ++rt) {
        s4[rt][0] = MFMA(qf[rt][1], kf01, MFMA(qf[rt][0], kf00, zero4));
        s4[rt][1] = MFMA(qf[rt][1], kf11, MFMA(qf[rt][0], kf10, zero4));
      }
#pragma unroll
      for (int rt = 0; rt < 2; ++rt)
#pragma unroll
        for (int m = 0; m < 4; ++m)
          qer[rt][m] = MFMA(qf[rt][1], ef[m][1], MFMA(qf[rt][0], ef[m][0], zero4));
      __builtin_amdgcn_s_setprio(0);

      const int d0 = t0 - s0;
#pragma unroll
      for (int rt = 0; rt < 2; ++rt) {
        const int base = rt ? 0 : 1;            // rt0 uses m{2,3,4}, rt1 m{1,2,3}
#pragma unroll
        for (int j = 0; j < 4; ++j) {
          const int sl = rt * 16 + q * 4 + j;
          const int srcl = (q << 4) | ((47 + r - q * 4 - j) & 15);
          const float sh0 = __shfl(qer[rt][base + 0][j], srcl);
          const float sh1 = __shfl(qer[rt][base + 1][j], srcl);
          const float sh2 = __shfl(qer[rt][base + 2][j], srcl);
          const bool hi = (r > q * 4 + j);      // iteration/rt/ct-invariant
          const float g0 = hi ? sh1 : sh0;
          const float g1 = hi ? sh2 : sh1;
          const float sv0 = s4[rt][0][j] + g0;  // Q pre-scaled by 1/8
          const float sv1 = s4[rt][1][j] + g1;
          const int a = sl - r;                 // unmasked iff a >= d0 (+16)
          const float p0 = (a >= d0)      ? __expf(sv0) : 0.f;
          const float p1 = (a >= d0 + 16) ? __expf(sv1) : 0.f;
          lpart[rt][j] += p0 + p1;
          p_lds[wv][sl][r]      = f2bf(p0);
          p_lds[wv][sl][16 + r] = f2bf(p1);
        }
      }

      bf16x8 vf0 = *(const bf16x8*)(VL + lane * 8);
      bf16x8 vf1 = *(const bf16x8*)(VL + 512 + lane * 8);
      bf16x8 vf2 = *(const bf16x8*)(VL + 1024 + lane * 8);
      bf16x8 vf3 = *(const bf16x8*)(VL + 1536 + lane * 8);
#pragma unroll
      for (int rt = 0; rt < 2; ++rt) {
        bf16x8 pf = *(const bf16x8*)(&p_lds[wv][rt * 16 + r][0] + q * 8);
        __builtin_amdgcn_s_setprio(1);
        oacc[rt][0] = MFMA(pf, vf0, oacc[rt][0]);
        oacc[rt][1] = MFMA(pf, vf1, oacc[rt][1]);
        oacc[rt][2] = MFMA(pf, vf2, oacc[rt][2]);
        oacc[rt][3] = MFMA(pf, vf3, oacc[rt][3]);
        __builtin_amdgcn_s_setprio(0);
      }
    }

    // epilogue: unnormalized partial sums
#pragma unroll
    for (int rt = 0; rt < 2; ++rt)
#pragma unroll
      for (int j = 0; j < 4; ++j) {
        float ls = lpart[rt][j];
#pragma unroll
        for (int d = 1; d < 16; d <<= 1) ls += __shfl_xor(ls, d);
        const int row = wv * 32 + rt * 16 + q * 4 + j;
#pragma unroll
        for (int dc = 0; dc < 4; ++dc)
          po[(size_t)row * 64 + dc * 16 + r] = oacc[rt][dc][j];
        if (r == 0) pl[row] = ls;
      }
  };

  const int TL = 15 - pairp, TS = pairp;
  {
    const size_t slot = ((size_t)bh * 16 + TL) * 2 + ab;
    run_strip(TL, pO + slot * 8192, pL + slot * 128);
  }
  {
    const size_t slot = ((size_t)bh * 16 + TS) * 2 + ab;
    run_strip(TS, pO + slot * 8192, pL + slot * 128);
  }
}

// ---------------------------------------------------------------- reduce ----
// out = (oA + oB) / (lA + lB) for every 128-row tile.
__global__ __launch_bounds__(256) void reduce_kernel(const float* __restrict__ pO,
                                                     const float* __restrict__ pL,
                                                     float* __restrict__ out) {
  const int slot = blockIdx.x;                  // bh*16 + tile
  const int bh = slot >> 4, tile = slot & 15;
  const int bb = bh >> 4, hh = bh & 15;
  const int tid = threadIdx.x;
  const int row0 = tid >> 3, c8 = (tid & 7) * 8;

  const float* pA = pO + (size_t)slot * 16384;
  const float* pB = pA + 8192;
  const float* lA = pL + (size_t)slot * 256;
  const float* lB = lA + 128;

#pragma unroll
  for (int rr = 0; rr < 4; ++rr) {
    const int row = row0 + rr * 32;
    const float inv = 1.0f / (lA[row] + lB[row]);
    const float* a = pA + row * 64 + c8;
    const float* b = pB + row * 64 + c8;
    float4 x0 = ((const float4*)a)[0], x1 = ((const float4*)a)[1];
    float4 y0 = ((const float4*)b)[0], y1 = ((const float4*)b)[1];
    float4 o0, o1;
    o0.x = (x0.x + y0.x) * inv; o0.y = (x0.y + y0.y) * inv;
    o0.z = (x0.z + y0.z) * inv; o0.w = (x0.w + y0.w) * inv;
    o1.x = (x1.x + y1.x) * inv; o1.y = (x1.y + y1.y) * inv;
    o1.z = (x1.z + y1.z) * inv; o1.w = (x1.w + y1.w) * inv;
    float* dst = out + ((size_t)(bb * SEQ_) + tile * 128 + row) * DMODEL + hh * DHEAD + c8;
    ((float4*)dst)[0] = o0;
    ((float4*)dst)[1] = o1;
  }
}

// ------------------------------------------------------------------ launch ---
extern "C" void kernel_launch(void* const* d_in, const int* in_sizes, int n_in,
                              void* d_out, int out_size, void* d_ws, size_t ws_size,
                              hipStream_t stream) {
  const float* query = (const float*)d_in[0];
  const float* key   = (const float*)d_in[1];
  const float* value = (const float*)d_in[2];
  const float* Wq    = (const float*)d_in[3];
  const float* bq    = (const float*)d_in[4];
  const float* Wk    = (const float*)d_in[5];
  const float* bk    = (const float*)d_in[6];
  const float* Wv    = (const float*)d_in[7];
  const float* bv    = (const float*)d_in[8];
  const float* Er    = (const float*)d_in[9];

  char* ws = (char*)d_ws;
  unsigned short* qb   = (unsigned short*)(ws + (0u  << 20));  // (B,H,S,64) bf16  8MB
  unsigned short* ktil = (unsigned short*)(ws + (8u  << 20));  // K frag-tiles     8MB
  unsigned short* vtil = (unsigned short*)(ws + (16u << 20));  // V frag-tiles     8MB
  float*          pO   = (float*)(ws + (24u << 20));           // partials 32MB [24,56)
  float*          pL   = (float*)(ws + (60u << 20));           // 512KB (dead Wvb)
  unsigned short* Xq   = (unsigned short*)(ws + (32u << 20));  // dead after proj3
  unsigned short* Xk   = (unsigned short*)(ws + (40u << 20));
  unsigned short* Xv   = (unsigned short*)(ws + (48u << 20));
  unsigned short* Wqb  = (unsigned short*)(ws + (56u << 20));  // (D, D) bf16 2MB
  unsigned short* Wkb  = (unsigned short*)(ws + (58u << 20));
  unsigned short* Wvb  = (unsigned short*)(ws + (60u << 20));  // clobbered by pL post-proj (ok)
  unsigned short* Erb  = (unsigned short*)(ws + (62u << 20));  // (2048, 64) 256KB

  conv3_kernel<<<dim3(2048, 3), 256, 0, stream>>>(query, key, value, Xq, Xk, Xv,
                                                  2 * SEQ_ * DMODEL);
  conv3_kernel<<<dim3(512, 3), 256, 0, stream>>>(Wq, Wk, Wv, Wqb, Wkb, Wvb,
                                                 DMODEL * DMODEL);
  conv3_kernel<<<dim3(64, 1), 256, 0, stream>>>(Er, Er, Er, Erb, Erb, Erb,
                                                SEQ_ * DHEAD);

  proj3_kernel<<<dim3(32, 8, 3), 256, 0, stream>>>(Xq, Xk, Xv, Wqb, Wkb, Wvb,
                                                   bq, bk, bv, qb, ktil, vtil);

  attn_kernel<<<dim3(512), 256, 0, stream>>>(qb, ktil, vtil, Erb, pO, pL);

  reduce_kernel<<<dim3(512), 256, 0, stream>>>(pO, pL, (float*)d_out);
}